// Round 1
// baseline (176.891 us; speedup 1.0000x reference)
//
#include <hip/hip_runtime.h>

// ST-GCN spatial graph conv, fused:
//   out[n,c,t,w] = sum_k sum_v (b[k*64+c] + sum_ci x[n,ci,t,v]*W[k*64+c,ci]) * A[k,v,w]
//
// Block = (n, t-tile of 4). 256 threads: tt = tid>>6 (wave id), c = tid&63 (lane).
// LDS: x slice [64ci][4tt][28pad], A [3][25][28pad], W_k^T [64ci][64o] staged per k.
// freg[25] = f row (bias folded in), acc[25] = out row, both in registers.

#define N_   32
#define CIN  64
#define T_   300
#define V_   25
#define K_   3
#define COUT 64
#define TT   4
#define VP   28   // padded row length (16B-aligned rows for b128 reads)

__global__ __launch_bounds__(256, 2) void gcn_fused(
    const float* __restrict__ x, const float* __restrict__ W,
    const float* __restrict__ bias, const float* __restrict__ A,
    float* __restrict__ out)
{
    __shared__ float x_s[CIN * TT * VP];     // 7168 floats
    __shared__ float A_s[K_ * V_ * VP];      // 2100 floats
    __shared__ float Wk_s[CIN * COUT];       // 4096 floats

    const int tid = threadIdx.x;
    const int bx  = blockIdx.x;
    const int n   = bx / (T_ / TT);
    const int t0  = (bx % (T_ / TT)) * TT;

    // ---- stage x slice: for each ci, 100 contiguous floats (t0..t0+3, v 0..24),
    //      16B-aligned in global; scatter into padded [ci][tt][28] LDS layout.
    for (int idx = tid; idx < CIN * V_; idx += 256) {   // 1600 float4s
        const int ci = idx / V_;
        const int j  = idx % V_;                         // float4 index within 100-float row
        const float4 xv = *reinterpret_cast<const float4*>(
            x + ((size_t)(n * CIN + ci) * T_ + t0) * V_ + j * 4);
        const float* xe = reinterpret_cast<const float*>(&xv);
        #pragma unroll
        for (int e = 0; e < 4; ++e) {
            const int p  = j * 4 + e;                    // 0..99
            const int tt = p / V_, v = p % V_;
            x_s[(ci * TT + tt) * VP + v] = xe[e];
        }
    }
    // ---- stage A (scalar; tiny, L2-resident)
    for (int idx = tid; idx < K_ * V_ * V_; idx += 256) {
        const int k = idx / (V_ * V_);
        const int r = (idx / V_) % V_;
        const int w = idx % V_;
        A_s[(k * V_ + r) * VP + w] = A[idx];
    }
    __syncthreads();

    const int c  = tid & 63;   // lane
    const int tt = tid >> 6;   // wave

    float acc[V_];
    #pragma unroll
    for (int w = 0; w < V_; ++w) acc[w] = 0.f;

    for (int k = 0; k < K_; ++k) {
        __syncthreads();   // previous k's Wk_s readers done
        // stage W_k transposed: Wk_s[ci][o] = W[(k*64+o)*64 + ci]
        for (int idx = tid; idx < COUT * (CIN / 4); idx += 256) {  // 1024 float4s
            const int o = idx / (CIN / 4);
            const int j = idx % (CIN / 4);
            const float4 wv = *reinterpret_cast<const float4*>(
                W + ((size_t)(k * COUT + o)) * CIN + j * 4);
            const float* we = reinterpret_cast<const float*>(&wv);
            #pragma unroll
            for (int e = 0; e < 4; ++e)
                Wk_s[(j * 4 + e) * COUT + o] = we[e];
        }
        __syncthreads();

        // ---- f row for (k, c, tt): freg[v] = b + sum_ci W^T[ci][c] * x[ci][tt][v]
        float freg[V_];
        const float bk = bias[k * COUT + c];
        #pragma unroll
        for (int v = 0; v < V_; ++v) freg[v] = bk;

        for (int ci = 0; ci < CIN; ++ci) {
            const float wv = Wk_s[ci * COUT + c];                 // lane-stride-1, conflict-free
            const float4* xr4 = reinterpret_cast<const float4*>(&x_s[(ci * TT + tt) * VP]);
            float4 xq[7];                                         // 28 floats, broadcast reads
            #pragma unroll
            for (int q = 0; q < 7; ++q) xq[q] = xr4[q];
            const float* xr = reinterpret_cast<const float*>(xq);
            #pragma unroll
            for (int v = 0; v < V_; ++v) freg[v] = fmaf(wv, xr[v], freg[v]);
        }

        // ---- aggregate: acc[w] += freg[v] * A[k][v][w]
        for (int v = 0; v < V_; ++v) {
            const float4* ar4 = reinterpret_cast<const float4*>(&A_s[(k * V_ + v) * VP]);
            float4 aq[7];
            #pragma unroll
            for (int q = 0; q < 7; ++q) aq[q] = ar4[q];
            const float* ar = reinterpret_cast<const float*>(aq);
            const float fv = freg[v];
            #pragma unroll
            for (int w = 0; w < V_; ++w) acc[w] = fmaf(fv, ar[w], acc[w]);
        }
    }

    // ---- store out[n][c][t0+tt][0..24]
    float* op = out + ((size_t)(n * COUT + c) * T_ + t0 + tt) * V_;
    #pragma unroll
    for (int w = 0; w < V_; ++w) op[w] = acc[w];
}

extern "C" void kernel_launch(void* const* d_in, const int* in_sizes, int n_in,
                              void* d_out, int out_size, void* d_ws, size_t ws_size,
                              hipStream_t stream) {
    const float* x    = (const float*)d_in[0];
    const float* W    = (const float*)d_in[1];
    const float* bias = (const float*)d_in[2];
    const float* A    = (const float*)d_in[3];
    float* out = (float*)d_out;

    dim3 grid(N_ * (T_ / TT));   // 32 * 75 = 2400
    dim3 block(256);
    hipLaunchKernelGGL(gcn_fused, grid, block, 0, stream, x, W, bias, A, out);
}

// Round 2
// 52.241 us; speedup vs baseline: 3.3861x; 3.3861x over previous
//
#include <hip/hip_runtime.h>

// ST-GCN spatial graph conv, fused two-stage MFMA (bf16 in, f32 accum).
//   Stage1: F^T[tv][kc] = X^T[tv][ci] @ W^T[ci][kc]   (per block: n, 4 t's)
//   Stage2: out_t^T[w][c] = Ahat[w][khat] @ F_t[khat][c], khat = k*32+v (padded)
//
// LDS: As [32][96] bf16, bias f32[192], union{ Xs[128][64] + Ws[192][64] | Fs[192][128] } bf16.
// Swizzles: Xs/Ws 16B-chunk ^= (row&7); Fs 16B-chunk ^= (row&15). Verified read==write.

#define CIN   64
#define T_    300
#define V_    25
#define OC    192     // K*C_OUT
#define COUT  64
#define TB    4       // t's per block
#define NBLK  (32 * (T_ / TB))   // 2400

typedef short  bf16x8 __attribute__((ext_vector_type(8)));
typedef float  f32x4  __attribute__((ext_vector_type(4)));
typedef unsigned int u32x2 __attribute__((ext_vector_type(2)));

__device__ __forceinline__ unsigned short f2bf(float f) {   // RNE f32->bf16
    unsigned u = __float_as_uint(f);
    u += 0x7FFFu + ((u >> 16) & 1u);
    return (unsigned short)(u >> 16);
}

#define AS_OFF   0        // 6144 B : Ahat[32][96] bf16
#define BIAS_OFF 6144     // 768 B  : bias f32[192]
#define XS_OFF   6912     // 16384 B: Xs[128 tv][64 ci] bf16 (rows 128B, 8 chunks)
#define WS_OFF   23296    // 24576 B: Ws[192 o][64 ci] bf16
#define FS_OFF   6912     // 49152 B: Fs[192 kc][128 tv] bf16 (rows 256B, 16 chunks) — aliases Xs+Ws
#define SMEM_BYTES 56064

__global__ __launch_bounds__(512, 4) void gcn_mfma(
    const float* __restrict__ x, const float* __restrict__ W,
    const float* __restrict__ bias, const float* __restrict__ A,
    float* __restrict__ out)
{
    __shared__ __align__(16) unsigned char smem[SMEM_BYTES];
    unsigned short* As_p  = reinterpret_cast<unsigned short*>(smem + AS_OFF);
    float*          bias_p = reinterpret_cast<float*>(smem + BIAS_OFF);

    const int tid = threadIdx.x;
    const int bx  = blockIdx.x;
    const int n   = bx / (T_ / TB);
    const int t0  = (bx % (T_ / TB)) * TB;

    // ---- stage Xs: x[n][ci][t0*25 .. +100) -> bf16 Xs[t*32+v][ci], swizzled
    for (int idx4 = tid; idx4 < CIN * 25; idx4 += 512) {      // 1600 float4s
        const int ci = idx4 / 25, j = idx4 % 25;
        const float4 xv = *reinterpret_cast<const float4*>(
            x + (size_t)(n * CIN + ci) * 7500 + t0 * 25 + j * 4);
        const float* xe = reinterpret_cast<const float*>(&xv);
        #pragma unroll
        for (int e = 0; e < 4; ++e) {
            const int p = j * 4 + e, tt = p / 25, v = p % 25;
            const int row = tt * 32 + v;
            const int byte = XS_OFF + row * 128 + ((((ci >> 3) ^ (row & 7)) << 4)) + (ci & 7) * 2;
            *reinterpret_cast<unsigned short*>(smem + byte) = f2bf(xe[e]);
        }
    }
    // zero the v=25..31 pad rows of Xs (keeps F pads finite)
    {
        bf16x8 zz = (bf16x8)0;
        for (int idx = tid; idx < TB * 7 * 8; idx += 512) {
            const int tt = idx / 56, rr = (idx / 8) % 7, j = idx & 7;
            const int row = tt * 32 + 25 + rr;
            *reinterpret_cast<bf16x8*>(smem + XS_OFF + row * 128 + ((j ^ (row & 7)) << 4)) = zz;
        }
    }
    // ---- stage Ws: W[o][ci] f32 -> bf16 Ws[o][ci] (natural layout), swizzled 16B chunks
    for (int ch = tid; ch < OC * 8; ch += 512) {              // 1536 b128 chunks
        const int o = ch >> 3, j = ch & 7;
        const float4 wa = *reinterpret_cast<const float4*>(W + (size_t)o * 64 + j * 8);
        const float4 wb = *reinterpret_cast<const float4*>(W + (size_t)o * 64 + j * 8 + 4);
        const float* wea = reinterpret_cast<const float*>(&wa);
        const float* web = reinterpret_cast<const float*>(&wb);
        bf16x8 s;
        #pragma unroll
        for (int e = 0; e < 4; ++e) { s[e] = (short)f2bf(wea[e]); s[4 + e] = (short)f2bf(web[e]); }
        *reinterpret_cast<bf16x8*>(smem + WS_OFF + o * 128 + ((j ^ (o & 7)) << 4)) = s;
    }
    // ---- stage Ahat[w][k*32+v] = A[k][v][w], zero-padded (v>=25, w>=25)
    for (int idx = tid; idx < 32 * 96; idx += 512) {
        const int wq = idx / 96, kh = idx % 96;
        const int k = kh >> 5, v = kh & 31;
        const float val = (wq < 25 && v < 25) ? A[k * 625 + v * 25 + wq] : 0.f;
        As_p[wq * 96 + kh] = f2bf(val);
    }
    if (tid < OC) bias_p[tid] = bias[tid];
    __syncthreads();

    const int wv = tid >> 6, l = tid & 63, lr = l & 15, lq = l >> 4;

    // ---- stage 1: wave wv owns M-tile wv (tv rows 16wv..16wv+15), all 12 N-tiles
    f32x4 acc[12];
    #pragma unroll
    for (int i = 0; i < 12; ++i) acc[i] = (f32x4){0.f, 0.f, 0.f, 0.f};

    const int rA = wv * 16 + lr;
    #pragma unroll
    for (int ks = 0; ks < 2; ++ks) {
        const bf16x8 afr = *reinterpret_cast<bf16x8*>(
            smem + XS_OFF + rA * 128 + (((ks * 4 + lq) ^ (rA & 7)) << 4));
        #pragma unroll
        for (int nn = 0; nn < 12; ++nn) {
            const int o = nn * 16 + lr;
            const bf16x8 bfr = *reinterpret_cast<bf16x8*>(
                smem + WS_OFF + o * 128 + (((ks * 4 + lq) ^ (o & 7)) << 4));
            acc[nn] = __builtin_amdgcn_mfma_f32_16x16x32_bf16(afr, bfr, acc[nn], 0, 0, 0);
        }
    }

    // preload stage-2 A-frags (Ahat region is not aliased)
    const int mt = wv >> 2, nc = wv & 3;
    bf16x8 afr2[3];
    #pragma unroll
    for (int ks = 0; ks < 3; ++ks)
        afr2[ks] = *reinterpret_cast<bf16x8*>(
            smem + AS_OFF + (mt * 16 + lr) * 192 + ks * 64 + lq * 16);

    __syncthreads();   // all stage-1 LDS reads done before Fs overwrites Xs/Ws

    // ---- write F = acc + bias to Fs[kc][tv] bf16, swizzled (b64 per tile)
    const int tvb = wv * 16 + lq * 4;
    #pragma unroll
    for (int nn = 0; nn < 12; ++nn) {
        const int kc = nn * 16 + lr;
        const float bb = bias_p[kc];
        const unsigned short h0 = f2bf(acc[nn][0] + bb), h1 = f2bf(acc[nn][1] + bb);
        const unsigned short h2 = f2bf(acc[nn][2] + bb), h3 = f2bf(acc[nn][3] + bb);
        u32x2 pk;
        pk[0] = (unsigned)h0 | ((unsigned)h1 << 16);
        pk[1] = (unsigned)h2 | ((unsigned)h3 << 16);
        const int byte = FS_OFF + kc * 256 + ((((tvb >> 3) ^ (kc & 15)) << 4)) + (tvb & 7) * 2;
        *reinterpret_cast<u32x2*>(smem + byte) = pk;
    }
    __syncthreads();

    // ---- stage 2: wave -> out tile (mt: w-rows, nc: c-cols), loop t
    const int c  = nc * 16 + lr;
    const int w0 = mt * 16 + lq * 4;
    #pragma unroll
    for (int t = 0; t < TB; ++t) {
        f32x4 a2 = (f32x4){0.f, 0.f, 0.f, 0.f};
        #pragma unroll
        for (int ks = 0; ks < 3; ++ks) {
            const int kc = ks * 64 + c;
            const bf16x8 bfr = *reinterpret_cast<bf16x8*>(
                smem + FS_OFF + kc * 256 + ((((t * 4 + lq) ^ (kc & 15)) << 4)));
            a2 = __builtin_amdgcn_mfma_f32_16x16x32_bf16(afr2[ks], bfr, a2, 0, 0, 0);
        }
        float* op = out + ((size_t)(n * COUT + c) * T_ + (t0 + t)) * V_;
        if (w0 + 3 < V_) {
            #pragma unroll
            for (int e = 0; e < 4; ++e) op[w0 + e] = a2[e];
        } else {
            #pragma unroll
            for (int e = 0; e < 4; ++e) if (w0 + e < V_) op[w0 + e] = a2[e];
        }
    }
}

extern "C" void kernel_launch(void* const* d_in, const int* in_sizes, int n_in,
                              void* d_out, int out_size, void* d_ws, size_t ws_size,
                              hipStream_t stream) {
    const float* x    = (const float*)d_in[0];
    const float* W    = (const float*)d_in[1];
    const float* bias = (const float*)d_in[2];
    const float* A    = (const float*)d_in[3];
    float* out = (float*)d_out;

    hipLaunchKernelGGL(gcn_mfma, dim3(NBLK), dim3(512), 0, stream, x, W, bias, A, out);
}

// Round 3
// 49.482 us; speedup vs baseline: 3.5749x; 1.0558x over previous
//
#include <hip/hip_runtime.h>
#include <hip/hip_bf16.h>

// ST-GCN spatial graph conv, fused two-stage MFMA (bf16 in, f32 accum).
//   Stage1: F^T[tv][kc] = X^T[tv][ci] @ W^T[ci][kc]   (per block: n, 4 t's)
//           A-frags loaded DIRECT from global x (no Xs LDS).
//   Stage2: out_t^T[w][c] = Ahat[w][khat] @ F_t[khat][c], khat = k*32+v (padded;
//           Ahat zeros kill v>=25 pad garbage in F).
//
// LDS: Fs[192 kc][128 tv] bf16 swizzled [0,49152) — Ws[192][64] bf16 swizzled
// aliased inside [0,24576) (dead after stage-1); bias f32[192] @49152;
// As[32 w][104 pad] bf16 @49920. Total 56576 B -> 2 blocks/CU.

#define CIN   64
#define T_    300
#define V_    25
#define OC    192     // K*C_OUT
#define COUT  64
#define TB    4
#define NBLK  (32 * (T_ / TB))   // 2400

typedef short  bf16x8 __attribute__((ext_vector_type(8)));
typedef float  f32x4  __attribute__((ext_vector_type(4)));
typedef unsigned int u32x2 __attribute__((ext_vector_type(2)));

__device__ __forceinline__ unsigned short cvt_bf16(float f) {   // HW RNE cvt (m240)
    __hip_bfloat16 h = __float2bfloat16(f);
    union { __hip_bfloat16 h; unsigned short u; } cv;
    cv.h = h;
    return cv.u;
}

#define WS_OFF    0        // 24576 B: Ws[192 o][64 ci] bf16, chunk ^= (o&7)   (aliased by Fs)
#define FS_OFF    0        // 49152 B: Fs[192 kc][128 tv] bf16, chunk ^= (kc&15)
#define BIAS_OFF  49152    // 768 B  : bias f32[192]
#define AS_OFF    49920    // 6656 B : As[32 w][104 khat-pad] bf16
#define SMEM_BYTES 56576

__global__ __launch_bounds__(512, 4) void gcn_mfma(
    const float* __restrict__ x, const float* __restrict__ W,
    const float* __restrict__ bias, const float* __restrict__ A,
    float* __restrict__ out)
{
    __shared__ __align__(16) unsigned char smem[SMEM_BYTES];

    const int tid = threadIdx.x;
    const int bx  = blockIdx.x;
    const int n   = bx / (T_ / TB);
    const int t0  = (bx % (T_ / TB)) * TB;

    const int wv = tid >> 6, l = tid & 63, lr = l & 15, lq = l >> 4;

    // ---- issue direct x loads for stage-1 A-frags (independent of LDS staging)
    //      wave wv covers tv rows wv*16+lr:  tt = wv>>1, v = (wv&1)*16 + lr
    const int tt = wv >> 1;
    const int v  = (wv & 1) * 16 + lr;
    const int vc = v > 24 ? 24 : v;          // clamp; pad rows killed by Ahat zeros
    const float* xb = x + ((size_t)(n * CIN + lq * 8) * T_ + (t0 + tt)) * V_ + vc;
    float xr[16];
    #pragma unroll
    for (int ks = 0; ks < 2; ++ks)
        #pragma unroll
        for (int e = 0; e < 8; ++e)
            xr[ks * 8 + e] = xb[(size_t)(ks * 32 + e) * (T_ * V_)];

    // ---- stage Ws: W[o][ci] f32 -> bf16, natural layout, 16B chunks ^= (o&7)
    for (int ch = tid; ch < OC * 8; ch += 512) {              // 1536 chunks
        const int o = ch >> 3, j = ch & 7;
        const float4 wa = *reinterpret_cast<const float4*>(W + (size_t)o * CIN + j * 8);
        const float4 wb = *reinterpret_cast<const float4*>(W + (size_t)o * CIN + j * 8 + 4);
        const float* wea = reinterpret_cast<const float*>(&wa);
        const float* web = reinterpret_cast<const float*>(&wb);
        bf16x8 s;
        #pragma unroll
        for (int e = 0; e < 4; ++e) {
            s[e]     = (short)cvt_bf16(wea[e]);
            s[4 + e] = (short)cvt_bf16(web[e]);
        }
        *reinterpret_cast<bf16x8*>(smem + WS_OFF + o * 128 + ((j ^ (o & 7)) << 4)) = s;
    }
    // ---- stage Ahat[w][k*32+v] = A[k][v][w], zero-padded, rows padded to 104
    for (int idx = tid; idx < 32 * 96; idx += 512) {
        const int wq = idx / 96, kh = idx % 96;
        const int k = kh >> 5, vv = kh & 31;
        const float val = (wq < V_ && vv < V_) ? A[k * (V_ * V_) + vv * V_ + wq] : 0.f;
        *reinterpret_cast<unsigned short*>(smem + AS_OFF + (wq * 104 + kh) * 2) = cvt_bf16(val);
    }
    if (tid < OC) *reinterpret_cast<float*>(smem + BIAS_OFF + tid * 4) = bias[tid];
    __syncthreads();

    // ---- stage 1: wave wv owns M-tile wv, all 12 N-tiles
    f32x4 acc[12];
    #pragma unroll
    for (int i = 0; i < 12; ++i) acc[i] = (f32x4){0.f, 0.f, 0.f, 0.f};

    #pragma unroll
    for (int ks = 0; ks < 2; ++ks) {
        bf16x8 afr;
        #pragma unroll
        for (int e = 0; e < 8; ++e) afr[e] = (short)cvt_bf16(xr[ks * 8 + e]);
        #pragma unroll
        for (int nn = 0; nn < 12; ++nn) {
            const int o = nn * 16 + lr;
            const bf16x8 bfr = *reinterpret_cast<bf16x8*>(
                smem + WS_OFF + o * 128 + (((ks * 4 + lq) ^ (o & 7)) << 4));
            acc[nn] = __builtin_amdgcn_mfma_f32_16x16x32_bf16(afr, bfr, acc[nn], 0, 0, 0);
        }
    }

    __syncthreads();   // stage-1 Ws reads done before Fs overwrites

    // ---- write F = acc + bias to Fs[kc][tv] bf16, swizzled
    const int tvb = wv * 16 + lq * 4;
    #pragma unroll
    for (int nn = 0; nn < 12; ++nn) {
        const int kc = nn * 16 + lr;
        const float bb = *reinterpret_cast<const float*>(smem + BIAS_OFF + kc * 4);
        const unsigned short h0 = cvt_bf16(acc[nn][0] + bb), h1 = cvt_bf16(acc[nn][1] + bb);
        const unsigned short h2 = cvt_bf16(acc[nn][2] + bb), h3 = cvt_bf16(acc[nn][3] + bb);
        u32x2 pk;
        pk[0] = (unsigned)h0 | ((unsigned)h1 << 16);
        pk[1] = (unsigned)h2 | ((unsigned)h3 << 16);
        const int byte = FS_OFF + kc * 256 + ((((tvb >> 3) ^ (kc & 15)) << 4)) + (tvb & 7) * 2;
        *reinterpret_cast<u32x2*>(smem + byte) = pk;
    }
    __syncthreads();

    // ---- stage 2: wave -> out tile (mt: w-rows, nc: c-cols), loop t
    const int mt = wv >> 2, nc = wv & 3;
    bf16x8 afr2[3];
    #pragma unroll
    for (int ks = 0; ks < 3; ++ks)
        afr2[ks] = *reinterpret_cast<bf16x8*>(
            smem + AS_OFF + ((mt * 16 + lr) * 104 + ks * 32 + lq * 8) * 2);

    const int c  = nc * 16 + lr;
    const int w0 = mt * 16 + lq * 4;
    #pragma unroll
    for (int t = 0; t < TB; ++t) {
        f32x4 a2 = (f32x4){0.f, 0.f, 0.f, 0.f};
        #pragma unroll
        for (int ks = 0; ks < 3; ++ks) {
            const int kc = ks * 64 + c;
            const bf16x8 bfr = *reinterpret_cast<bf16x8*>(
                smem + FS_OFF + kc * 256 + ((((t * 4 + lq) ^ (kc & 15)) << 4)));
            a2 = __builtin_amdgcn_mfma_f32_16x16x32_bf16(afr2[ks], bfr, a2, 0, 0, 0);
        }
        float* op = out + ((size_t)(n * COUT + c) * T_ + (t0 + t)) * V_;
        if (w0 + 3 < V_) {
            #pragma unroll
            for (int e = 0; e < 4; ++e) op[w0 + e] = a2[e];
        } else {
            #pragma unroll
            for (int e = 0; e < 4; ++e) if (w0 + e < V_) op[w0 + e] = a2[e];
        }
    }
}

extern "C" void kernel_launch(void* const* d_in, const int* in_sizes, int n_in,
                              void* d_out, int out_size, void* d_ws, size_t ws_size,
                              hipStream_t stream) {
    const float* x    = (const float*)d_in[0];
    const float* W    = (const float*)d_in[1];
    const float* bias = (const float*)d_in[2];
    const float* A    = (const float*)d_in[3];
    float* out = (float*)d_out;

    hipLaunchKernelGGL(gcn_mfma, dim3(NBLK), dim3(512), 0, stream, x, W, bias, A, out);
}